// Round 1
// baseline (1949.409 us; speedup 1.0000x reference)
//
#include <hip/hip_runtime.h>
#include <math.h>

#define NVV 25000
#define NCC 12500
#define NEE 250000

// ---------- float <-> monotonic uint key (for atomicMax on floats) ----------
__device__ __forceinline__ unsigned f2key(float f) {
  unsigned u = __float_as_uint(f);
  return (u & 0x80000000u) ? ~u : (u | 0x80000000u);
}
__device__ __forceinline__ float key2f(unsigned k) {
  unsigned u = (k & 0x80000000u) ? (k & 0x7FFFFFFFu) : ~k;
  return __uint_as_float(u);
}

// ---------- generic fp32 GEMM: out[N,128] = X[N,K] @ W[K,128] (+bias)(+relu) ----------
// 256 threads, tile 32 rows x 128 cols, 4x4 micro-tile per thread.
__global__ __launch_bounds__(256) void gemm128(
    const float* __restrict__ X, const float* __restrict__ W,
    const float* __restrict__ bias, float* __restrict__ out,
    int N, int K, int relu_flag) {
  __shared__ float Xs[144 * 36];  // transposed tile, row stride 36 (16B-aligned, bank-spread)
  int tid = threadIdx.x;
  int row0 = blockIdx.x * 32;

  int total = 32 * K;
  for (int idx = tid; idx < total; idx += 256) {
    int r = idx / K;
    int k = idx - r * K;
    int row = row0 + r;
    Xs[k * 36 + r] = (row < N) ? X[(size_t)row * K + k] : 0.0f;
  }
  __syncthreads();

  int tx = tid & 31;   // col group: cols 4*tx .. 4*tx+3
  int ty = tid >> 5;   // row group: rows 4*ty .. 4*ty+3
  float4 a0 = {0,0,0,0}, a1 = {0,0,0,0}, a2 = {0,0,0,0}, a3 = {0,0,0,0};
  const float* Wp = W + tx * 4;

  for (int k = 0; k < K; ++k) {
    float4 xv = *(const float4*)&Xs[k * 36 + ty * 4];
    float4 wv = *(const float4*)&Wp[(size_t)k * 128];
    a0.x = fmaf(xv.x, wv.x, a0.x); a0.y = fmaf(xv.x, wv.y, a0.y);
    a0.z = fmaf(xv.x, wv.z, a0.z); a0.w = fmaf(xv.x, wv.w, a0.w);
    a1.x = fmaf(xv.y, wv.x, a1.x); a1.y = fmaf(xv.y, wv.y, a1.y);
    a1.z = fmaf(xv.y, wv.z, a1.z); a1.w = fmaf(xv.y, wv.w, a1.w);
    a2.x = fmaf(xv.z, wv.x, a2.x); a2.y = fmaf(xv.z, wv.y, a2.y);
    a2.z = fmaf(xv.z, wv.z, a2.z); a2.w = fmaf(xv.z, wv.w, a2.w);
    a3.x = fmaf(xv.w, wv.x, a3.x); a3.y = fmaf(xv.w, wv.y, a3.y);
    a3.z = fmaf(xv.w, wv.z, a3.z); a3.w = fmaf(xv.w, wv.w, a3.w);
  }

  float4 bv = {0,0,0,0};
  if (bias) bv = *(const float4*)&bias[tx * 4];
  float4 accs[4] = {a0, a1, a2, a3};
  #pragma unroll
  for (int i = 0; i < 4; ++i) {
    int row = row0 + ty * 4 + i;
    if (row < N) {
      float4 o;
      o.x = accs[i].x + bv.x; o.y = accs[i].y + bv.y;
      o.z = accs[i].z + bv.z; o.w = accs[i].w + bv.w;
      if (relu_flag) {
        o.x = fmaxf(o.x, 0.f); o.y = fmaxf(o.y, 0.f);
        o.z = fmaxf(o.z, 0.f); o.w = fmaxf(o.w, 0.f);
      }
      *(float4*)&out[(size_t)row * 128 + tx * 4] = o;
    }
  }
}

// ---------- concat [A | B] -> out[N, dA+dB] ----------
__global__ void build_comb2(const float* __restrict__ A, const float* __restrict__ B,
                            float* __restrict__ out, int N, int dA, int dB) {
  int idx = blockIdx.x * blockDim.x + threadIdx.x;
  int d = dA + dB;
  if (idx >= N * d) return;
  int row = idx / d, c = idx - row * d;
  out[idx] = (c < dA) ? A[(size_t)row * dA + c] : B[(size_t)row * dB + (c - dA)];
}

// ---------- edge_comb[NE,136] = [edge_learned(128), lo, hi, def, wo(5)] ----------
__global__ void build_edge_comb(const float* __restrict__ el, const float* __restrict__ lo,
                                const float* __restrict__ hi, const float* __restrict__ dm,
                                const float* __restrict__ wo, float* __restrict__ out) {
  int idx = blockIdx.x * blockDim.x + threadIdx.x;
  if (idx >= NEE * 136) return;
  int row = idx / 136;
  int c = idx - row * 136;
  float v;
  if (c < 128)      v = el[(size_t)row * 128 + c];
  else if (c == 128) v = lo[row];
  else if (c == 129) v = hi[row];
  else if (c == 130) v = dm[row];
  else               v = wo[(size_t)row * 5 + (c - 131)];
  out[idx] = v;
}

// ---------- init segment buffers: amax=-inf key, denom=0, cnt=0, agg=0 ----------
__global__ void seg_init(unsigned* __restrict__ amax, float* __restrict__ denom,
                         float* __restrict__ cnt, float* __restrict__ agg, int n) {
  int i = blockIdx.x * blockDim.x + threadIdx.x;
  if (i < n) { amax[i] = f2key(-INFINITY); denom[i] = 0.0f; cnt[i] = 0.0f; }
  if (i < n * 128) agg[i] = 0.0f;
}

// ---------- alpha[e] = dot(q[dst], k[src]+ee[e]) / sqrt(128); atomicMax amax[dst] ----------
__global__ __launch_bounds__(256) void attn_alpha(
    const float* __restrict__ q, const float* __restrict__ k,
    const float* __restrict__ ee, const int* __restrict__ src,
    const int* __restrict__ dst, float* __restrict__ alpha,
    unsigned* __restrict__ amax, int nE) {
  int e = blockIdx.x * 4 + (threadIdx.x >> 6);
  if (e >= nE) return;
  int lane = threadIdx.x & 63;
  int s = src[e], d = dst[e];
  float2 qv = *(const float2*)&q[(size_t)d * 128 + lane * 2];
  float2 kv = *(const float2*)&k[(size_t)s * 128 + lane * 2];
  float2 ev = *(const float2*)&ee[(size_t)e * 128 + lane * 2];
  float p = qv.x * (kv.x + ev.x) + qv.y * (kv.y + ev.y);
  #pragma unroll
  for (int off = 32; off > 0; off >>= 1) p += __shfl_down(p, off, 64);
  if (lane == 0) {
    float a = p * 0.08838834764831845f;  // 1/sqrt(128)
    alpha[e] = a;
    atomicMax(amax + d, f2key(a));
  }
}

// ---------- ex = exp(alpha - amax[dst]); denom += ex; cnt += 1 ----------
__global__ void attn_ex(float* __restrict__ alpha, const unsigned* __restrict__ amax,
                        float* __restrict__ denom, float* __restrict__ cnt,
                        const int* __restrict__ dst, int nE) {
  int e = blockIdx.x * blockDim.x + threadIdx.x;
  if (e >= nE) return;
  int d = dst[e];
  float x = expf(alpha[e] - key2f(amax[d]));
  alpha[e] = x;
  atomicAdd(&denom[d], x);
  atomicAdd(&cnt[d], 1.0f);
}

// ---------- agg[dst] += (v[src]+ee[e]) * ex/denom[dst] ----------
__global__ __launch_bounds__(256) void attn_msg(
    const float* __restrict__ v, const float* __restrict__ ee,
    const float* __restrict__ ex, const float* __restrict__ denom,
    const int* __restrict__ src, const int* __restrict__ dst,
    float* __restrict__ agg, int nE) {
  int e = blockIdx.x * 2 + (threadIdx.x >> 7);
  if (e >= nE) return;
  int c = threadIdx.x & 127;
  int s = src[e], d = dst[e];
  float a = ex[e] / denom[d];
  float val = (v[(size_t)s * 128 + c] + ee[(size_t)e * 128 + c]) * a;
  atomicAdd(&agg[(size_t)d * 128 + c], val);
}

// ---------- out = relu(agg/max(cnt,1) + skip); also refresh comb[:, :128] ----------
__global__ void finalize_node(const float* __restrict__ agg, const float* __restrict__ cnt,
                              const float* __restrict__ skip, float* __restrict__ outd,
                              float* __restrict__ comb, int n) {
  int idx = blockIdx.x * blockDim.x + threadIdx.x;
  if (idx >= n * 128) return;
  int r = idx >> 7, c = idx & 127;
  float o = agg[idx] / fmaxf(cnt[r], 1.0f) + skip[idx];
  o = fmaxf(o, 0.0f);
  outd[idx] = o;
  comb[(size_t)r * 144 + c] = o;
}

// ---------- hidden = relu(t_e + vcW[ev] + ccW[ec] + b1), in-place on t_e ----------
__global__ void edge_hidden(float* __restrict__ te, const float* __restrict__ vcW,
                            const float* __restrict__ ccW, const float* __restrict__ b1,
                            const int* __restrict__ ev, const int* __restrict__ ec) {
  size_t idx = (size_t)blockIdx.x * blockDim.x + threadIdx.x;
  if (idx >= (size_t)NEE * 128) return;
  int e = (int)(idx >> 7);
  int c = (int)(idx & 127);
  float t = te[idx] + vcW[(size_t)ev[e] * 128 + c] + ccW[(size_t)ec[e] * 128 + c] + b1[c];
  te[idx] = fmaxf(t, 0.0f);
}

static inline void gemm(const float* X, const float* W, const float* b, float* out,
                        int N, int K, int relu, hipStream_t s) {
  int blocks = (N + 31) / 32;
  hipLaunchKernelGGL(gemm128, dim3(blocks), dim3(256), 0, s, X, W, b, out, N, K, relu);
}

extern "C" void kernel_launch(void* const* d_in, const int* in_sizes, int n_in,
                              void* d_out, int out_size, void* d_ws, size_t ws_size,
                              hipStream_t stream) {
  const float* var_learned = (const float*)d_in[0];
  const float* var_lp      = (const float*)d_in[1];
  const float* con_learned = (const float*)d_in[2];
  const float* con_lp      = (const float*)d_in[3];
  const float* edge_learned= (const float*)d_in[4];
  const float* lo          = (const float*)d_in[5];
  const float* hi          = (const float*)d_in[6];
  const float* dm          = (const float*)d_in[7];
  const float* wo          = (const float*)d_in[8];
  const float* cu_Wq = (const float*)d_in[9],  *cu_bq = (const float*)d_in[10];
  const float* cu_Wk = (const float*)d_in[11], *cu_bk = (const float*)d_in[12];
  const float* cu_Wv = (const float*)d_in[13], *cu_bv = (const float*)d_in[14];
  const float* cu_We = (const float*)d_in[15];
  const float* cu_Ws = (const float*)d_in[16], *cu_bs = (const float*)d_in[17];
  const float* vu_Wq = (const float*)d_in[18], *vu_bq = (const float*)d_in[19];
  const float* vu_Wk = (const float*)d_in[20], *vu_bk = (const float*)d_in[21];
  const float* vu_Wv = (const float*)d_in[22], *vu_bv = (const float*)d_in[23];
  const float* vu_We = (const float*)d_in[24];
  const float* vu_Ws = (const float*)d_in[25], *vu_bs = (const float*)d_in[26];
  const float* eu_vW1 = (const float*)d_in[27], *eu_vb1 = (const float*)d_in[28];
  const float* eu_vW2 = (const float*)d_in[29], *eu_vb2 = (const float*)d_in[30];
  const float* eu_cW1 = (const float*)d_in[31], *eu_cb1 = (const float*)d_in[32];
  const float* eu_cW2 = (const float*)d_in[33], *eu_cb2 = (const float*)d_in[34];
  const float* eu_eW1 = (const float*)d_in[35], *eu_eb1 = (const float*)d_in[36];
  const float* eu_eW2 = (const float*)d_in[37], *eu_eb2 = (const float*)d_in[38];
  const int* eiv = (const int*)d_in[39];
  const int* eic = (const int*)d_in[40];

  float* out_var  = (float*)d_out;                       // [NV,128]
  float* out_con  = out_var + (size_t)NVV * 128;         // [NC,128]
  float* out_edge = out_con + (size_t)NCC * 128;         // [NE,128]

  // ---- workspace arena (floats) ----
  float* ws = (float*)d_ws;
  size_t off = 0;
  float* edge_comb = ws + off; off += (size_t)NEE * 136;  // persists all stages
  float* eebuf     = ws + off; off += (size_t)NEE * 128;  // ee_cu -> ee_vu -> t_e
  float* alpha     = ws + off; off += NEE;                // alpha -> ex in place
  float* var_comb  = ws + off; off += (size_t)NVV * 144;  // cols 0:128 refreshed after var update
  float* con_comb  = ws + off; off += (size_t)NCC * 144;  // cols 0:128 refreshed after con update
  float* bufV1     = ws + off; off += (size_t)NVV * 128;  // kA -> qB/skipB -> vhid/vcW
  float* bufV2     = ws + off; off += (size_t)NVV * 128;  // vA -> aggB -> vc
  float* bufC1     = ws + off; off += (size_t)NCC * 128;  // qA/skipA -> kB -> chid/ccW
  float* bufC2     = ws + off; off += (size_t)NCC * 128;  // aggA -> vB -> cc
  unsigned* amax   = (unsigned*)(ws + off); off += NVV;
  float* denom     = ws + off; off += NVV;
  float* cnt       = ws + off; off += NVV;
  (void)off; (void)ws_size; (void)in_sizes; (void)n_in; (void)out_size;

  const int T = 256;

  // ---- build combined features ----
  build_comb2<<<(NVV * 144 + T - 1) / T, T, 0, stream>>>(var_learned, var_lp, var_comb, NVV, 128, 16);
  build_comb2<<<(NCC * 144 + T - 1) / T, T, 0, stream>>>(con_learned, con_lp, con_comb, NCC, 128, 16);
  build_edge_comb<<<(NEE * 136 + T - 1) / T, T, 0, stream>>>(edge_learned, lo, hi, dm, wo, edge_comb);

  // ================= Stage A: con update (src=var, dst=con) =================
  gemm(con_comb, cu_Wq, cu_bq, bufC1, NCC, 144, 0, stream);     // q_c
  gemm(var_comb, cu_Wk, cu_bk, bufV1, NVV, 144, 0, stream);     // k_v
  gemm(var_comb, cu_Wv, cu_bv, bufV2, NVV, 144, 0, stream);     // v_v
  gemm(edge_comb, cu_We, nullptr, eebuf, NEE, 136, 0, stream);  // ee
  seg_init<<<(NCC * 128 + T - 1) / T, T, 0, stream>>>(amax, denom, cnt, bufC2, NCC);
  attn_alpha<<<(NEE + 3) / 4, 256, 0, stream>>>(bufC1, bufV1, eebuf, eiv, eic, alpha, amax, NEE);
  attn_ex<<<(NEE + T - 1) / T, T, 0, stream>>>(alpha, amax, denom, cnt, eic, NEE);
  gemm(con_comb, cu_Ws, cu_bs, bufC1, NCC, 144, 0, stream);     // skip_c (q_c dead)
  attn_msg<<<(NEE + 1) / 2, 256, 0, stream>>>(bufV2, eebuf, alpha, denom, eiv, eic, bufC2, NEE);
  finalize_node<<<(NCC * 128 + T - 1) / T, T, 0, stream>>>(bufC2, cnt, bufC1, out_con, con_comb, NCC);

  // ================= Stage B: var update (src=new con, dst=var) =================
  gemm(var_comb, vu_Wq, vu_bq, bufV1, NVV, 144, 0, stream);     // q_v
  gemm(con_comb, vu_Wk, vu_bk, bufC1, NCC, 144, 0, stream);     // k_c (new con_comb)
  gemm(con_comb, vu_Wv, vu_bv, bufC2, NCC, 144, 0, stream);     // v_c
  gemm(edge_comb, vu_We, nullptr, eebuf, NEE, 136, 0, stream);  // ee2
  seg_init<<<(NVV * 128 + T - 1) / T, T, 0, stream>>>(amax, denom, cnt, bufV2, NVV);
  attn_alpha<<<(NEE + 3) / 4, 256, 0, stream>>>(bufV1, bufC1, eebuf, eic, eiv, alpha, amax, NEE);
  attn_ex<<<(NEE + T - 1) / T, T, 0, stream>>>(alpha, amax, denom, cnt, eiv, NEE);
  gemm(var_comb, vu_Ws, vu_bs, bufV1, NVV, 144, 0, stream);     // skip_v (q_v dead)
  attn_msg<<<(NEE + 1) / 2, 256, 0, stream>>>(bufC2, eebuf, alpha, denom, eic, eiv, bufV2, NEE);
  finalize_node<<<(NVV * 128 + T - 1) / T, T, 0, stream>>>(bufV2, cnt, bufV1, out_var, var_comb, NVV);

  // ================= Edge stage =================
  // vc = relu(relu(var_comb2 @ vW1 + b) @ vW2 + b); vcW = vc @ eW1[136:264]
  gemm(var_comb, eu_vW1, eu_vb1, bufV1, NVV, 144, 1, stream);
  gemm(bufV1, eu_vW2, eu_vb2, bufV2, NVV, 128, 1, stream);                  // vc
  gemm(bufV2, eu_eW1 + 136 * 128, nullptr, bufV1, NVV, 128, 0, stream);     // vcW
  gemm(con_comb, eu_cW1, eu_cb1, bufC1, NCC, 144, 1, stream);
  gemm(bufC1, eu_cW2, eu_cb2, bufC2, NCC, 128, 1, stream);                  // cc
  gemm(bufC2, eu_eW1 + 264 * 128, nullptr, bufC1, NCC, 128, 0, stream);     // ccW
  gemm(edge_comb, eu_eW1, nullptr, eebuf, NEE, 136, 0, stream);             // t_e
  edge_hidden<<<(int)(((size_t)NEE * 128 + T - 1) / T), T, 0, stream>>>(eebuf, bufV1, bufC1, eu_eb1, eiv, eic);
  gemm(eebuf, eu_eW2, eu_eb2, out_edge, NEE, 128, 1, stream);               // edge_new
}

// Round 2
// 1261.976 us; speedup vs baseline: 1.5447x; 1.5447x over previous
//
#include <hip/hip_runtime.h>
#include <math.h>

#define NVV 25000
#define NCC 12500
#define NEE 250000
#define KP 160   // padded K for all bf16 GEMM operands (covers K=128,136,144)

typedef short bf16x8 __attribute__((ext_vector_type(8)));
typedef float f32x4 __attribute__((ext_vector_type(4)));

// ---------- helpers ----------
__device__ __forceinline__ unsigned short f2bf(float f) {  // RNE fp32->bf16
  unsigned u = __float_as_uint(f);
  u += 0x7fffu + ((u >> 16) & 1u);
  return (unsigned short)(u >> 16);
}
__device__ __forceinline__ unsigned f2key(float f) {
  unsigned u = __float_as_uint(f);
  return (u & 0x80000000u) ? ~u : (u | 0x80000000u);
}
__device__ __forceinline__ float key2f(unsigned k) {
  unsigned u = (k & 0x80000000u) ? (k & 0x7FFFFFFFu) : ~k;
  return __uint_as_float(u);
}
__device__ __forceinline__ void gll16(const unsigned short* g, unsigned short* l) {
  // async global->LDS, 16B per lane; LDS dst = wave-uniform base + lane*16
  __builtin_amdgcn_global_load_lds(
      (const __attribute__((address_space(1))) unsigned int*)(const void*)g,
      (__attribute__((address_space(3))) unsigned int*)(void*)l, 16, 0, 0);
}

// ---------- bf16 MFMA GEMM: out[N,128] = X[N,160]bf16 @ W[160,128] ----------
// WT is W transposed+converted: WT[col][k], [128,160] bf16. 128x128 tile,
// 4 waves each compute 64x64 via 4x4 grid of 16x16x32 MFMAs. K-loop: 5 steps.
__global__ __launch_bounds__(256) void gemm_mfma(
    const unsigned short* __restrict__ X, const unsigned short* __restrict__ WT,
    const float* __restrict__ bias, float* __restrict__ outf,
    unsigned short* __restrict__ outb,  // optional bf16 copy [N,160], pads zeroed
    int N, int relu_flag) {
  __shared__ unsigned short As[128 * 32];  // [row][q][8] : chunk c=row*4+q at c*16B
  __shared__ unsigned short Bs[128 * 32];  // [col][q][8]
  int tid = threadIdx.x;
  int lane = tid & 63, wave = tid >> 6;
  int row0 = blockIdx.x * 128;

  // staging: chunk c handled by thread: c=tid (inst0), c=tid+256 (inst1)
  int q = tid & 3;
  int rA0 = row0 + (tid >> 2);        if (rA0 >= N) rA0 = N - 1;
  int rA1 = row0 + ((tid + 256) >> 2); if (rA1 >= N) rA1 = N - 1;
  const unsigned short* gA0 = X + (size_t)rA0 * KP + q * 8;
  const unsigned short* gA1 = X + (size_t)rA1 * KP + q * 8;
  int colB = tid >> 2;
  const unsigned short* gB0 = WT + (size_t)colB * KP + q * 8;
  const unsigned short* gB1 = WT + (size_t)(colB + 64) * KP + q * 8;
  unsigned short* ldsA0 = As + (size_t)(wave * 64) * 8;
  unsigned short* ldsA1 = As + (size_t)(256 + wave * 64) * 8;
  unsigned short* ldsB0 = Bs + (size_t)(wave * 64) * 8;
  unsigned short* ldsB1 = Bs + (size_t)(256 + wave * 64) * 8;

  int wm = (wave & 1) * 64, wn = (wave >> 1) * 64;
  int fr = lane & 15, fq = lane >> 4;

  f32x4 acc[4][4];
  #pragma unroll
  for (int mi = 0; mi < 4; ++mi)
    #pragma unroll
    for (int ni = 0; ni < 4; ++ni) {
      acc[mi][ni][0] = 0.f; acc[mi][ni][1] = 0.f;
      acc[mi][ni][2] = 0.f; acc[mi][ni][3] = 0.f;
    }

  for (int k0 = 0; k0 < KP; k0 += 32) {
    gll16(gA0 + k0, ldsA0); gll16(gA1 + k0, ldsA1);
    gll16(gB0 + k0, ldsB0); gll16(gB1 + k0, ldsB1);
    __syncthreads();  // drains vmcnt -> staged data visible
    bf16x8 av[4], bv[4];
    #pragma unroll
    for (int mi = 0; mi < 4; ++mi)
      av[mi] = *(const bf16x8*)&As[(wm + mi * 16 + fr) * 32 + fq * 8];
    #pragma unroll
    for (int ni = 0; ni < 4; ++ni)
      bv[ni] = *(const bf16x8*)&Bs[(wn + ni * 16 + fr) * 32 + fq * 8];
    #pragma unroll
    for (int mi = 0; mi < 4; ++mi)
      #pragma unroll
      for (int ni = 0; ni < 4; ++ni)
        acc[mi][ni] = __builtin_amdgcn_mfma_f32_16x16x32_bf16(av[mi], bv[ni], acc[mi][ni], 0, 0, 0);
    __syncthreads();  // all reads done before next stage overwrites
  }

  // epilogue: C/D layout col=lane&15, row=(lane>>4)*4+reg
  #pragma unroll
  for (int mi = 0; mi < 4; ++mi) {
    #pragma unroll
    for (int ni = 0; ni < 4; ++ni) {
      int gcol = wn + ni * 16 + fr;
      float bvv = bias ? bias[gcol] : 0.0f;
      #pragma unroll
      for (int r = 0; r < 4; ++r) {
        int grow = row0 + wm + mi * 16 + fq * 4 + r;
        if (grow < N) {
          float o = acc[mi][ni][r] + bvv;
          if (relu_flag) o = fmaxf(o, 0.f);
          if (outf) outf[(size_t)grow * 128 + gcol] = o;
          if (outb) outb[(size_t)grow * KP + gcol] = f2bf(o);
        }
      }
    }
    if (outb && wn == 0) {  // zero the K-pad columns 128..159
      #pragma unroll
      for (int r = 0; r < 4; ++r) {
        int grow = row0 + wm + mi * 16 + fq * 4 + r;
        if (grow < N) {
          outb[(size_t)grow * KP + 128 + fr] = 0;
          outb[(size_t)grow * KP + 144 + fr] = 0;
        }
      }
    }
  }
}

// ---------- build bf16 combined features ----------
__global__ void build_node_bf(const float* __restrict__ learned, const float* __restrict__ lp,
                              unsigned short* __restrict__ out, int N) {
  int idx = blockIdx.x * blockDim.x + threadIdx.x;
  if (idx >= N * 40) return;
  int row = idx / 40, c4 = idx - row * 40;
  int c = c4 * 4;
  ushort4 o;
  if (c4 < 32) {
    const float* p = learned + (size_t)row * 128 + c;
    o.x = f2bf(p[0]); o.y = f2bf(p[1]); o.z = f2bf(p[2]); o.w = f2bf(p[3]);
  } else if (c4 < 36) {
    const float* p = lp + (size_t)row * 16 + (c - 128);
    o.x = f2bf(p[0]); o.y = f2bf(p[1]); o.z = f2bf(p[2]); o.w = f2bf(p[3]);
  } else { o.x = o.y = o.z = o.w = 0; }
  *(ushort4*)&out[(size_t)row * KP + c] = o;
}

__global__ void build_edge_bf(const float* __restrict__ el, const float* __restrict__ lo,
                              const float* __restrict__ hi, const float* __restrict__ dm,
                              const float* __restrict__ wo, unsigned short* __restrict__ out) {
  int idx = blockIdx.x * blockDim.x + threadIdx.x;
  if (idx >= NEE * 40) return;
  int row = idx / 40, c4 = idx - row * 40;
  int c = c4 * 4;
  ushort4 o;
  if (c4 < 32) {
    const float* p = el + (size_t)row * 128 + c;
    o.x = f2bf(p[0]); o.y = f2bf(p[1]); o.z = f2bf(p[2]); o.w = f2bf(p[3]);
  } else if (c4 == 32) {
    o.x = f2bf(lo[row]); o.y = f2bf(hi[row]); o.z = f2bf(dm[row]);
    o.w = f2bf(wo[(size_t)row * 5 + 0]);
  } else if (c4 == 33) {
    const float* p = wo + (size_t)row * 5;
    o.x = f2bf(p[1]); o.y = f2bf(p[2]); o.z = f2bf(p[3]); o.w = f2bf(p[4]);
  } else { o.x = o.y = o.z = o.w = 0; }
  *(ushort4*)&out[(size_t)row * KP + c] = o;
}

// ---------- weight transpose + convert: W[K,128] -> WT[128,160] bf16 ----------
struct WJobs {
  const float* W[18];
  unsigned short* O[18];
  int K[18];
};
__global__ void convert_weights(WJobs j) {
  int b = blockIdx.x;
  int job = b / 80;
  int i = (b - job * 80) * 256 + threadIdx.x;  // 0..20479
  int col = i / KP;
  int k = i - col * KP;
  int K = j.K[job];
  j.O[job][(size_t)col * KP + k] =
      (k < K) ? f2bf(j.W[job][(size_t)k * 128 + col]) : (unsigned short)0;
}

// ---------- attention (fp32, unchanged from R1) ----------
__global__ void seg_init(unsigned* __restrict__ amax, float* __restrict__ denom,
                         float* __restrict__ cnt, float* __restrict__ agg, int n) {
  int i = blockIdx.x * blockDim.x + threadIdx.x;
  if (i < n) { amax[i] = f2key(-INFINITY); denom[i] = 0.0f; cnt[i] = 0.0f; }
  if (i < n * 128) agg[i] = 0.0f;
}

__global__ __launch_bounds__(256) void attn_alpha(
    const float* __restrict__ qv_, const float* __restrict__ kv_,
    const float* __restrict__ ee, const int* __restrict__ src,
    const int* __restrict__ dst, float* __restrict__ alpha,
    unsigned* __restrict__ amax, int nE) {
  int e = blockIdx.x * 4 + (threadIdx.x >> 6);
  if (e >= nE) return;
  int lane = threadIdx.x & 63;
  int s = src[e], d = dst[e];
  float2 qv = *(const float2*)&qv_[(size_t)d * 128 + lane * 2];
  float2 kv = *(const float2*)&kv_[(size_t)s * 128 + lane * 2];
  float2 ev = *(const float2*)&ee[(size_t)e * 128 + lane * 2];
  float p = qv.x * (kv.x + ev.x) + qv.y * (kv.y + ev.y);
  #pragma unroll
  for (int off = 32; off > 0; off >>= 1) p += __shfl_down(p, off, 64);
  if (lane == 0) {
    float a = p * 0.08838834764831845f;
    alpha[e] = a;
    atomicMax(amax + d, f2key(a));
  }
}

__global__ void attn_ex(float* __restrict__ alpha, const unsigned* __restrict__ amax,
                        float* __restrict__ denom, float* __restrict__ cnt,
                        const int* __restrict__ dst, int nE) {
  int e = blockIdx.x * blockDim.x + threadIdx.x;
  if (e >= nE) return;
  int d = dst[e];
  float x = expf(alpha[e] - key2f(amax[d]));
  alpha[e] = x;
  atomicAdd(&denom[d], x);
  atomicAdd(&cnt[d], 1.0f);
}

__global__ __launch_bounds__(256) void attn_msg(
    const float* __restrict__ v, const float* __restrict__ ee,
    const float* __restrict__ ex, const float* __restrict__ denom,
    const int* __restrict__ src, const int* __restrict__ dst,
    float* __restrict__ agg, int nE) {
  int e = blockIdx.x * 2 + (threadIdx.x >> 7);
  if (e >= nE) return;
  int c = threadIdx.x & 127;
  int s = src[e], d = dst[e];
  float a = ex[e] / denom[d];
  float val = (v[(size_t)s * 128 + c] + ee[(size_t)e * 128 + c]) * a;
  atomicAdd(&agg[(size_t)d * 128 + c], val);
}

// ---------- out = relu(agg/max(cnt,1)+skip); refresh bf16 comb cols 0:128 ----------
__global__ void finalize_node(const float* __restrict__ agg, const float* __restrict__ cnt,
                              const float* __restrict__ skip, float* __restrict__ outd,
                              unsigned short* __restrict__ comb, int n) {
  int idx = blockIdx.x * blockDim.x + threadIdx.x;
  if (idx >= n * 128) return;
  int r = idx >> 7, c = idx & 127;
  float o = agg[idx] / fmaxf(cnt[r], 1.0f) + skip[idx];
  o = fmaxf(o, 0.0f);
  outd[idx] = o;
  comb[(size_t)r * KP + c] = f2bf(o);
}

// ---------- edge hidden = relu(t_e + vcW[ev] + ccW[ec] + b1) -> bf16 [NE,160] ----------
__global__ void edge_hidden_bf(const float* __restrict__ te, const float* __restrict__ vcW,
                               const float* __restrict__ ccW, const float* __restrict__ b1,
                               const int* __restrict__ ev, const int* __restrict__ ec,
                               unsigned short* __restrict__ out) {
  int idx = blockIdx.x * blockDim.x + threadIdx.x;
  if (idx >= NEE * 40) return;
  int e = idx / 40, c4 = idx - e * 40;
  int c = c4 * 4;
  ushort4 o;
  if (c4 < 32) {
    int vi = ev[e], ci = ec[e];
    float4 t = *(const float4*)&te[(size_t)e * 128 + c];
    float4 a = *(const float4*)&vcW[(size_t)vi * 128 + c];
    float4 b = *(const float4*)&ccW[(size_t)ci * 128 + c];
    float4 bb = *(const float4*)&b1[c];
    o.x = f2bf(fmaxf(t.x + a.x + b.x + bb.x, 0.f));
    o.y = f2bf(fmaxf(t.y + a.y + b.y + bb.y, 0.f));
    o.z = f2bf(fmaxf(t.z + a.z + b.z + bb.z, 0.f));
    o.w = f2bf(fmaxf(t.w + a.w + b.w + bb.w, 0.f));
  } else { o.x = o.y = o.z = o.w = 0; }
  *(ushort4*)&out[(size_t)e * KP + c] = o;
}

static inline void gemm(const unsigned short* X, const unsigned short* WT, const float* bias,
                        float* outf, unsigned short* outb, int N, int relu, hipStream_t s) {
  gemm_mfma<<<(N + 127) / 128, 256, 0, s>>>(X, WT, bias, outf, outb, N, relu);
}

extern "C" void kernel_launch(void* const* d_in, const int* in_sizes, int n_in,
                              void* d_out, int out_size, void* d_ws, size_t ws_size,
                              hipStream_t stream) {
  const float* var_learned = (const float*)d_in[0];
  const float* var_lp      = (const float*)d_in[1];
  const float* con_learned = (const float*)d_in[2];
  const float* con_lp      = (const float*)d_in[3];
  const float* edge_learned= (const float*)d_in[4];
  const float* lo          = (const float*)d_in[5];
  const float* hi          = (const float*)d_in[6];
  const float* dm          = (const float*)d_in[7];
  const float* wo          = (const float*)d_in[8];
  const float* cu_Wq = (const float*)d_in[9],  *cu_bq = (const float*)d_in[10];
  const float* cu_Wk = (const float*)d_in[11], *cu_bk = (const float*)d_in[12];
  const float* cu_Wv = (const float*)d_in[13], *cu_bv = (const float*)d_in[14];
  const float* cu_We = (const float*)d_in[15];
  const float* cu_Ws = (const float*)d_in[16], *cu_bs = (const float*)d_in[17];
  const float* vu_Wq = (const float*)d_in[18], *vu_bq = (const float*)d_in[19];
  const float* vu_Wk = (const float*)d_in[20], *vu_bk = (const float*)d_in[21];
  const float* vu_Wv = (const float*)d_in[22], *vu_bv = (const float*)d_in[23];
  const float* vu_We = (const float*)d_in[24];
  const float* vu_Ws = (const float*)d_in[25], *vu_bs = (const float*)d_in[26];
  const float* eu_vW1 = (const float*)d_in[27], *eu_vb1 = (const float*)d_in[28];
  const float* eu_vW2 = (const float*)d_in[29], *eu_vb2 = (const float*)d_in[30];
  const float* eu_cW1 = (const float*)d_in[31], *eu_cb1 = (const float*)d_in[32];
  const float* eu_cW2 = (const float*)d_in[33], *eu_cb2 = (const float*)d_in[34];
  const float* eu_eW1 = (const float*)d_in[35], *eu_eb1 = (const float*)d_in[36];
  const float* eu_eW2 = (const float*)d_in[37], *eu_eb2 = (const float*)d_in[38];
  const int* eiv = (const int*)d_in[39];
  const int* eic = (const int*)d_in[40];

  float* out_var  = (float*)d_out;
  float* out_con  = out_var + (size_t)NVV * 128;
  float* out_edge = out_con + (size_t)NCC * 128;

  // ---- workspace arena ----
  char* w = (char*)d_ws;
  auto alloc = [&](size_t bytes) { char* p = w; w += (bytes + 255) & ~(size_t)255; return p; };
  unsigned short* edge_comb_bf = (unsigned short*)alloc((size_t)NEE * KP * 2);  // later: te_bf alias
  float* eebuf  = (float*)alloc((size_t)NEE * 128 * 4);   // ee_cu -> ee_vu -> t_e f32
  float* alpha  = (float*)alloc((size_t)NEE * 4);
  unsigned short* var_comb_bf = (unsigned short*)alloc((size_t)NVV * KP * 2);
  unsigned short* con_comb_bf = (unsigned short*)alloc((size_t)NCC * KP * 2);
  unsigned short* hidV_bf = (unsigned short*)alloc((size_t)NVV * KP * 2);
  unsigned short* vc_bf   = (unsigned short*)alloc((size_t)NVV * KP * 2);
  unsigned short* hidC_bf = (unsigned short*)alloc((size_t)NCC * KP * 2);
  unsigned short* cc_bf   = (unsigned short*)alloc((size_t)NCC * KP * 2);
  float* bufV1 = (float*)alloc((size_t)NVV * 128 * 4);
  float* bufV2 = (float*)alloc((size_t)NVV * 128 * 4);
  float* bufC1 = (float*)alloc((size_t)NCC * 128 * 4);
  float* bufC2 = (float*)alloc((size_t)NCC * 128 * 4);
  unsigned short* WTbase = (unsigned short*)alloc((size_t)18 * 128 * KP * 2);
  unsigned* amax = (unsigned*)alloc((size_t)NVV * 4);
  float* denom = (float*)alloc((size_t)NVV * 4);
  float* cnt   = (float*)alloc((size_t)NVV * 4);
  unsigned short* te_bf = edge_comb_bf;  // edge_comb dead before edge_hidden writes
  (void)ws_size; (void)in_sizes; (void)n_in; (void)out_size;

  unsigned short* WT[18];
  for (int i = 0; i < 18; ++i) WT[i] = WTbase + (size_t)i * 128 * KP;
  WJobs jobs;
  const float* Wsrc[18] = {cu_Wq, cu_Wk, cu_Wv, cu_We, cu_Ws,
                           vu_Wq, vu_Wk, vu_Wv, vu_We, vu_Ws,
                           eu_vW1, eu_vW2, eu_cW1, eu_cW2,
                           eu_eW1, eu_eW1 + 136 * 128, eu_eW1 + 264 * 128, eu_eW2};
  const int Ksrc[18] = {144, 144, 144, 136, 144, 144, 144, 144, 136, 144,
                        144, 128, 144, 128, 136, 128, 128, 128};
  for (int i = 0; i < 18; ++i) { jobs.W[i] = Wsrc[i]; jobs.O[i] = WT[i]; jobs.K[i] = Ksrc[i]; }

  const int T = 256;

  // ---- pre-passes: bf16 operands ----
  build_node_bf<<<(NVV * 40 + T - 1) / T, T, 0, stream>>>(var_learned, var_lp, var_comb_bf, NVV);
  build_node_bf<<<(NCC * 40 + T - 1) / T, T, 0, stream>>>(con_learned, con_lp, con_comb_bf, NCC);
  build_edge_bf<<<(NEE * 40 + T - 1) / T, T, 0, stream>>>(edge_learned, lo, hi, dm, wo, edge_comb_bf);
  convert_weights<<<18 * 80, T, 0, stream>>>(jobs);

  // ================= Stage A: con update (src=var, dst=con) =================
  gemm(con_comb_bf, WT[0], cu_bq, bufC1, nullptr, NCC, 0, stream);   // q_c
  gemm(var_comb_bf, WT[1], cu_bk, bufV1, nullptr, NVV, 0, stream);   // k_v
  gemm(var_comb_bf, WT[2], cu_bv, bufV2, nullptr, NVV, 0, stream);   // v_v
  gemm(edge_comb_bf, WT[3], nullptr, eebuf, nullptr, NEE, 0, stream);// ee
  seg_init<<<(NCC * 128 + T - 1) / T, T, 0, stream>>>(amax, denom, cnt, bufC2, NCC);
  attn_alpha<<<(NEE + 3) / 4, 256, 0, stream>>>(bufC1, bufV1, eebuf, eiv, eic, alpha, amax, NEE);
  attn_ex<<<(NEE + T - 1) / T, T, 0, stream>>>(alpha, amax, denom, cnt, eic, NEE);
  gemm(con_comb_bf, WT[4], cu_bs, bufC1, nullptr, NCC, 0, stream);   // skip_c (q dead)
  attn_msg<<<(NEE + 1) / 2, 256, 0, stream>>>(bufV2, eebuf, alpha, denom, eiv, eic, bufC2, NEE);
  finalize_node<<<(NCC * 128 + T - 1) / T, T, 0, stream>>>(bufC2, cnt, bufC1, out_con, con_comb_bf, NCC);

  // ================= Stage B: var update (src=new con, dst=var) =================
  gemm(var_comb_bf, WT[5], vu_bq, bufV1, nullptr, NVV, 0, stream);   // q_v
  gemm(con_comb_bf, WT[6], vu_bk, bufC1, nullptr, NCC, 0, stream);   // k_c
  gemm(con_comb_bf, WT[7], vu_bv, bufC2, nullptr, NCC, 0, stream);   // v_c
  gemm(edge_comb_bf, WT[8], nullptr, eebuf, nullptr, NEE, 0, stream);// ee2
  seg_init<<<(NVV * 128 + T - 1) / T, T, 0, stream>>>(amax, denom, cnt, bufV2, NVV);
  attn_alpha<<<(NEE + 3) / 4, 256, 0, stream>>>(bufV1, bufC1, eebuf, eic, eiv, alpha, amax, NEE);
  attn_ex<<<(NEE + T - 1) / T, T, 0, stream>>>(alpha, amax, denom, cnt, eiv, NEE);
  gemm(var_comb_bf, WT[9], vu_bs, bufV1, nullptr, NVV, 0, stream);   // skip_v
  attn_msg<<<(NEE + 1) / 2, 256, 0, stream>>>(bufC2, eebuf, alpha, denom, eic, eiv, bufV2, NEE);
  finalize_node<<<(NVV * 128 + T - 1) / T, T, 0, stream>>>(bufV2, cnt, bufV1, out_var, var_comb_bf, NVV);

  // ================= Edge stage =================
  gemm(var_comb_bf, WT[10], eu_vb1, nullptr, hidV_bf, NVV, 1, stream);
  gemm(hidV_bf, WT[11], eu_vb2, nullptr, vc_bf, NVV, 1, stream);     // vc
  gemm(vc_bf, WT[15], nullptr, bufV1, nullptr, NVV, 0, stream);      // vcW = vc @ eW1[136:264]
  gemm(con_comb_bf, WT[12], eu_cb1, nullptr, hidC_bf, NCC, 1, stream);
  gemm(hidC_bf, WT[13], eu_cb2, nullptr, cc_bf, NCC, 1, stream);     // cc
  gemm(cc_bf, WT[16], nullptr, bufC1, nullptr, NCC, 0, stream);      // ccW = cc @ eW1[264:392]
  gemm(edge_comb_bf, WT[14], nullptr, eebuf, nullptr, NEE, 0, stream); // t_e = edge_comb @ eW1[0:136]
  edge_hidden_bf<<<(NEE * 40 + T - 1) / T, T, 0, stream>>>(eebuf, bufV1, bufC1, eu_eb1, eiv, eic, te_bf);
  gemm(te_bf, WT[17], eu_eb2, out_edge, nullptr, NEE, 1, stream);    // edge_new
}

// Round 3
// 1182.965 us; speedup vs baseline: 1.6479x; 1.0668x over previous
//
#include <hip/hip_runtime.h>
#include <math.h>

#define NVV 25000
#define NCC 12500
#define NEE 250000
#define KP 160   // padded K for all bf16 GEMM inputs (covers K=128,136,144)

typedef short bf16x8 __attribute__((ext_vector_type(8)));
typedef float f32x4 __attribute__((ext_vector_type(4)));

// ---------- helpers ----------
__device__ __forceinline__ unsigned short f2bf(float f) {  // RNE fp32->bf16
  unsigned u = __float_as_uint(f);
  u += 0x7fffu + ((u >> 16) & 1u);
  return (unsigned short)(u >> 16);
}
__device__ __forceinline__ void gll16(const unsigned short* g, unsigned short* l) {
  __builtin_amdgcn_global_load_lds(
      (const __attribute__((address_space(1))) unsigned int*)(const void*)g,
      (__attribute__((address_space(3))) unsigned int*)(void*)l, 16, 0, 0);
}

// ---------- bf16 MFMA GEMM: out[N,128] = X[N,160]bf16 @ WT^T ----------
// Optional: f32 out, bf16 out (stride/pad), gather-add epilogue (edge stage).
__global__ __launch_bounds__(256) void gemm_mfma(
    const unsigned short* __restrict__ X, const unsigned short* __restrict__ WT,
    const float* __restrict__ bias, float* __restrict__ outf,
    unsigned short* __restrict__ outb, int outb_stride, int pad_flag,
    const float* __restrict__ gA, const float* __restrict__ gB,
    const int* __restrict__ giA, const int* __restrict__ giB,
    int N, int relu_flag) {
  __shared__ unsigned short As[128 * 32];
  __shared__ unsigned short Bs[128 * 32];
  int tid = threadIdx.x;
  int lane = tid & 63, wave = tid >> 6;
  int row0 = blockIdx.x * 128;

  int q = tid & 3;
  int rA0 = row0 + (tid >> 2);         if (rA0 >= N) rA0 = N - 1;
  int rA1 = row0 + ((tid + 256) >> 2); if (rA1 >= N) rA1 = N - 1;
  const unsigned short* gA0 = X + (size_t)rA0 * KP + q * 8;
  const unsigned short* gA1 = X + (size_t)rA1 * KP + q * 8;
  int colB = tid >> 2;
  const unsigned short* gB0 = WT + (size_t)colB * KP + q * 8;
  const unsigned short* gB1 = WT + (size_t)(colB + 64) * KP + q * 8;
  unsigned short* ldsA0 = As + (size_t)(wave * 64) * 8;
  unsigned short* ldsA1 = As + (size_t)(256 + wave * 64) * 8;
  unsigned short* ldsB0 = Bs + (size_t)(wave * 64) * 8;
  unsigned short* ldsB1 = Bs + (size_t)(256 + wave * 64) * 8;

  int wm = (wave & 1) * 64, wn = (wave >> 1) * 64;
  int fr = lane & 15, fq = lane >> 4;

  f32x4 acc[4][4];
  #pragma unroll
  for (int mi = 0; mi < 4; ++mi)
    #pragma unroll
    for (int ni = 0; ni < 4; ++ni) {
      acc[mi][ni][0] = 0.f; acc[mi][ni][1] = 0.f;
      acc[mi][ni][2] = 0.f; acc[mi][ni][3] = 0.f;
    }

  for (int k0 = 0; k0 < KP; k0 += 32) {
    gll16(gA0 + k0, ldsA0); gll16(gA1 + k0, ldsA1);
    gll16(gB0 + k0, ldsB0); gll16(gB1 + k0, ldsB1);
    __syncthreads();
    bf16x8 av[4], bv[4];
    #pragma unroll
    for (int mi = 0; mi < 4; ++mi)
      av[mi] = *(const bf16x8*)&As[(wm + mi * 16 + fr) * 32 + fq * 8];
    #pragma unroll
    for (int ni = 0; ni < 4; ++ni)
      bv[ni] = *(const bf16x8*)&Bs[(wn + ni * 16 + fr) * 32 + fq * 8];
    #pragma unroll
    for (int mi = 0; mi < 4; ++mi)
      #pragma unroll
      for (int ni = 0; ni < 4; ++ni)
        acc[mi][ni] = __builtin_amdgcn_mfma_f32_16x16x32_bf16(av[mi], bv[ni], acc[mi][ni], 0, 0, 0);
    __syncthreads();
  }

  #pragma unroll
  for (int mi = 0; mi < 4; ++mi) {
    #pragma unroll
    for (int ni = 0; ni < 4; ++ni) {
      int gcol = wn + ni * 16 + fr;
      float bvv = bias ? bias[gcol] : 0.0f;
      #pragma unroll
      for (int r = 0; r < 4; ++r) {
        int grow = row0 + wm + mi * 16 + fq * 4 + r;
        if (grow < N) {
          float o = acc[mi][ni][r] + bvv;
          if (gA) o += gA[(size_t)giA[grow] * 128 + gcol] + gB[(size_t)giB[grow] * 128 + gcol];
          if (relu_flag) o = fmaxf(o, 0.f);
          if (outf) outf[(size_t)grow * 128 + gcol] = o;
          if (outb) outb[(size_t)grow * outb_stride + gcol] = f2bf(o);
        }
      }
    }
    if (outb && pad_flag && wn == 0) {
      #pragma unroll
      for (int r = 0; r < 4; ++r) {
        int grow = row0 + wm + mi * 16 + fq * 4 + r;
        if (grow < N)
          for (int pc = 128 + fr; pc < outb_stride; pc += 16)
            outb[(size_t)grow * outb_stride + pc] = 0;
      }
    }
  }
}

// ---------- build bf16 combined features ----------
__global__ void build_node_bf(const float* __restrict__ learned, const float* __restrict__ lp,
                              unsigned short* __restrict__ out, int N) {
  int idx = blockIdx.x * blockDim.x + threadIdx.x;
  if (idx >= N * 40) return;
  int row = idx / 40, c4 = idx - row * 40;
  int c = c4 * 4;
  ushort4 o;
  if (c4 < 32) {
    const float* p = learned + (size_t)row * 128 + c;
    o.x = f2bf(p[0]); o.y = f2bf(p[1]); o.z = f2bf(p[2]); o.w = f2bf(p[3]);
  } else if (c4 < 36) {
    const float* p = lp + (size_t)row * 16 + (c - 128);
    o.x = f2bf(p[0]); o.y = f2bf(p[1]); o.z = f2bf(p[2]); o.w = f2bf(p[3]);
  } else { o.x = o.y = o.z = o.w = 0; }
  *(ushort4*)&out[(size_t)row * KP + c] = o;
}

__global__ void build_edge_bf(const float* __restrict__ el, const float* __restrict__ lo,
                              const float* __restrict__ hi, const float* __restrict__ dm,
                              const float* __restrict__ wo, unsigned short* __restrict__ out) {
  int idx = blockIdx.x * blockDim.x + threadIdx.x;
  if (idx >= NEE * 40) return;
  int row = idx / 40, c4 = idx - row * 40;
  int c = c4 * 4;
  ushort4 o;
  if (c4 < 32) {
    const float* p = el + (size_t)row * 128 + c;
    o.x = f2bf(p[0]); o.y = f2bf(p[1]); o.z = f2bf(p[2]); o.w = f2bf(p[3]);
  } else if (c4 == 32) {
    o.x = f2bf(lo[row]); o.y = f2bf(hi[row]); o.z = f2bf(dm[row]);
    o.w = f2bf(wo[(size_t)row * 5 + 0]);
  } else if (c4 == 33) {
    const float* p = wo + (size_t)row * 5;
    o.x = f2bf(p[1]); o.y = f2bf(p[2]); o.z = f2bf(p[3]); o.w = f2bf(p[4]);
  } else { o.x = o.y = o.z = o.w = 0; }
  *(ushort4*)&out[(size_t)row * KP + c] = o;
}

// ---------- weight transpose + convert ----------
struct WJobs {
  const float* W[18];
  unsigned short* O[18];
  int K[18];
};
__global__ void convert_weights(WJobs j) {
  int b = blockIdx.x;
  int job = b / 80;
  int i = (b - job * 80) * 256 + threadIdx.x;
  int col = i / KP;
  int k = i - col * KP;
  int K = j.K[job];
  j.O[job][(size_t)col * KP + k] =
      (k < K) ? f2bf(j.W[job][(size_t)k * 128 + col]) : (unsigned short)0;
}

// ---------- CSR construction ----------
__global__ void zero2(int* __restrict__ a, int na, int* __restrict__ b, int nb) {
  int i = blockIdx.x * blockDim.x + threadIdx.x;
  if (i < na) a[i] = 0;
  if (i < nb) b[i] = 0;
}
__global__ void hist2(const int* __restrict__ dc, int* __restrict__ cc,
                      const int* __restrict__ dv, int* __restrict__ cv, int nE) {
  int e = blockIdx.x * blockDim.x + threadIdx.x;
  if (e >= nE) return;
  atomicAdd(&cc[dc[e]], 1);
  atomicAdd(&cv[dv[e]], 1);
}
// single block 256 threads
__global__ void csr_scan(const int* __restrict__ counts, int* __restrict__ offsets,
                         int* __restrict__ cursor, int n) {
  __shared__ int part[256];
  int tid = threadIdx.x;
  int chunk = (n + 255) / 256;
  int lo = tid * chunk, hi = min(n, lo + chunk);
  int s = 0;
  for (int i = lo; i < hi; ++i) s += counts[i];
  part[tid] = s;
  __syncthreads();
  if (tid == 0) {
    int run = 0;
    for (int i = 0; i < 256; ++i) { int t = part[i]; part[i] = run; run += t; }
    offsets[n] = run;
  }
  __syncthreads();
  int base = part[tid];
  for (int i = lo; i < hi; ++i) { offsets[i] = base; cursor[i] = base; base += counts[i]; }
}
__global__ void csr_scatter(const int* __restrict__ dst, const int* __restrict__ src,
                            int* __restrict__ cursor, int* __restrict__ ce,
                            int* __restrict__ cs, int nE) {
  int e = blockIdx.x * blockDim.x + threadIdx.x;
  if (e >= nE) return;
  int pos = atomicAdd(&cursor[dst[e]], 1);
  ce[pos] = e;
  cs[pos] = src[e];
}

// ---------- fused flash-style segment attention: one wave per dst ----------
// out = relu( (sum_e (v[s]+ee)·exp(a-m)) / (l·deg) + skip ); also bf16 comb refresh
__global__ __launch_bounds__(256) void fused_attn(
    const float* __restrict__ qbuf, const float* __restrict__ kbuf,
    const float* __restrict__ vbuf, const unsigned short* __restrict__ ee,
    const int* __restrict__ offsets, const int* __restrict__ ce,
    const int* __restrict__ cs, const float* __restrict__ skip,
    float* __restrict__ outd, unsigned short* __restrict__ comb, int Nd) {
  int d = blockIdx.x * 4 + (threadIdx.x >> 6);
  if (d >= Nd) return;
  int lane = threadIdx.x & 63;
  int c = lane * 2;
  float2 qv = *(const float2*)&qbuf[(size_t)d * 128 + c];
  int beg = offsets[d], end = offsets[d + 1];
  float m = -INFINITY, l = 0.f;
  float ax = 0.f, ay = 0.f;
  for (int i = beg; i < end; ++i) {
    int e = ce[i], s = cs[i];
    unsigned eu = *(const unsigned*)&ee[(size_t)e * 128 + c];
    float e0 = __uint_as_float(eu << 16);
    float e1 = __uint_as_float(eu & 0xffff0000u);
    float2 kv = *(const float2*)&kbuf[(size_t)s * 128 + c];
    float2 vv = *(const float2*)&vbuf[(size_t)s * 128 + c];
    float p = qv.x * (kv.x + e0) + qv.y * (kv.y + e1);
    #pragma unroll
    for (int off = 1; off < 64; off <<= 1) p += __shfl_xor(p, off, 64);
    float alpha = p * 0.08838834764831845f;  // 1/sqrt(128)
    float mn = fmaxf(m, alpha);
    float scale = __expf(m - mn);            // first iter: exp(-inf)=0
    float w = __expf(alpha - mn);
    ax = ax * scale + (vv.x + e0) * w;
    ay = ay * scale + (vv.y + e1) * w;
    l = l * scale + w;
    m = mn;
  }
  int deg = end - beg;
  float inv = (deg > 0) ? 1.0f / (l * (float)deg) : 0.0f;
  float2 sk = *(const float2*)&skip[(size_t)d * 128 + c];
  float o0 = fmaxf(ax * inv + sk.x, 0.f);
  float o1 = fmaxf(ay * inv + sk.y, 0.f);
  *(float2*)&outd[(size_t)d * 128 + c] = make_float2(o0, o1);
  ushort2 ob; ob.x = f2bf(o0); ob.y = f2bf(o1);
  *(ushort2*)&comb[(size_t)d * KP + c] = ob;
}

static inline void gemm(const unsigned short* X, const unsigned short* WT, const float* bias,
                        float* outf, unsigned short* outb, int obstride, int pad,
                        const float* gA, const float* gB, const int* giA, const int* giB,
                        int N, int relu, hipStream_t s) {
  gemm_mfma<<<(N + 127) / 128, 256, 0, s>>>(X, WT, bias, outf, outb, obstride, pad,
                                            gA, gB, giA, giB, N, relu);
}

extern "C" void kernel_launch(void* const* d_in, const int* in_sizes, int n_in,
                              void* d_out, int out_size, void* d_ws, size_t ws_size,
                              hipStream_t stream) {
  const float* var_learned = (const float*)d_in[0];
  const float* var_lp      = (const float*)d_in[1];
  const float* con_learned = (const float*)d_in[2];
  const float* con_lp      = (const float*)d_in[3];
  const float* edge_learned= (const float*)d_in[4];
  const float* lo          = (const float*)d_in[5];
  const float* hi          = (const float*)d_in[6];
  const float* dm          = (const float*)d_in[7];
  const float* wo          = (const float*)d_in[8];
  const float* cu_Wq = (const float*)d_in[9],  *cu_bq = (const float*)d_in[10];
  const float* cu_Wk = (const float*)d_in[11], *cu_bk = (const float*)d_in[12];
  const float* cu_Wv = (const float*)d_in[13], *cu_bv = (const float*)d_in[14];
  const float* cu_We = (const float*)d_in[15];
  const float* cu_Ws = (const float*)d_in[16], *cu_bs = (const float*)d_in[17];
  const float* vu_Wq = (const float*)d_in[18], *vu_bq = (const float*)d_in[19];
  const float* vu_Wk = (const float*)d_in[20], *vu_bk = (const float*)d_in[21];
  const float* vu_Wv = (const float*)d_in[22], *vu_bv = (const float*)d_in[23];
  const float* vu_We = (const float*)d_in[24];
  const float* vu_Ws = (const float*)d_in[25], *vu_bs = (const float*)d_in[26];
  const float* eu_vW1 = (const float*)d_in[27], *eu_vb1 = (const float*)d_in[28];
  const float* eu_vW2 = (const float*)d_in[29], *eu_vb2 = (const float*)d_in[30];
  const float* eu_cW1 = (const float*)d_in[31], *eu_cb1 = (const float*)d_in[32];
  const float* eu_cW2 = (const float*)d_in[33], *eu_cb2 = (const float*)d_in[34];
  const float* eu_eW1 = (const float*)d_in[35], *eu_eb1 = (const float*)d_in[36];
  const float* eu_eW2 = (const float*)d_in[37], *eu_eb2 = (const float*)d_in[38];
  const int* eiv = (const int*)d_in[39];
  const int* eic = (const int*)d_in[40];

  float* out_var  = (float*)d_out;
  float* out_con  = out_var + (size_t)NVV * 128;
  float* out_edge = out_con + (size_t)NCC * 128;

  // ---- workspace arena ----
  char* w = (char*)d_ws;
  auto alloc = [&](size_t bytes) { char* p = w; w += (bytes + 255) & ~(size_t)255; return p; };
  unsigned short* edge_comb_bf = (unsigned short*)alloc((size_t)NEE * KP * 2);  // aliased te_bf
  unsigned short* ee_bf = (unsigned short*)alloc((size_t)NEE * 128 * 2);
  unsigned short* var_comb_bf = (unsigned short*)alloc((size_t)NVV * KP * 2);
  unsigned short* con_comb_bf = (unsigned short*)alloc((size_t)NCC * KP * 2);
  unsigned short* hidV_bf = (unsigned short*)alloc((size_t)NVV * KP * 2);
  unsigned short* vc_bf   = (unsigned short*)alloc((size_t)NVV * KP * 2);
  unsigned short* hidC_bf = (unsigned short*)alloc((size_t)NCC * KP * 2);
  unsigned short* cc_bf   = (unsigned short*)alloc((size_t)NCC * KP * 2);
  float* bufV1 = (float*)alloc((size_t)NVV * 128 * 4);
  float* bufV2 = (float*)alloc((size_t)NVV * 128 * 4);
  float* bufC1 = (float*)alloc((size_t)NCC * 128 * 4);
  float* bufC2 = (float*)alloc((size_t)NCC * 128 * 4);
  unsigned short* WTbase = (unsigned short*)alloc((size_t)18 * 128 * KP * 2);
  int* countsC = (int*)alloc((size_t)NCC * 4);
  int* countsV = (int*)alloc((size_t)NVV * 4);
  int* offC = (int*)alloc((size_t)(NCC + 1) * 4);
  int* curC = (int*)alloc((size_t)NCC * 4);
  int* offV = (int*)alloc((size_t)(NVV + 1) * 4);
  int* curV = (int*)alloc((size_t)NVV * 4);
  int* ceA = (int*)alloc((size_t)NEE * 4);  // conv A (dst=con): edge ids
  int* csA = (int*)alloc((size_t)NEE * 4);  //                   src (var) ids
  int* ceB = (int*)alloc((size_t)NEE * 4);  // conv B (dst=var)
  int* csB = (int*)alloc((size_t)NEE * 4);
  unsigned short* te_bf = edge_comb_bf;  // safe alias: gemm writes only its own rows
  (void)ws_size; (void)in_sizes; (void)n_in; (void)out_size;

  unsigned short* WT[18];
  for (int i = 0; i < 18; ++i) WT[i] = WTbase + (size_t)i * 128 * KP;
  WJobs jobs;
  const float* Wsrc[18] = {cu_Wq, cu_Wk, cu_Wv, cu_We, cu_Ws,
                           vu_Wq, vu_Wk, vu_Wv, vu_We, vu_Ws,
                           eu_vW1, eu_vW2, eu_cW1, eu_cW2,
                           eu_eW1, eu_eW1 + 136 * 128, eu_eW1 + 264 * 128, eu_eW2};
  const int Ksrc[18] = {144, 144, 144, 136, 144, 144, 144, 144, 136, 144,
                        144, 128, 144, 128, 136, 128, 128, 128};
  for (int i = 0; i < 18; ++i) { jobs.W[i] = Wsrc[i]; jobs.O[i] = WT[i]; jobs.K[i] = Ksrc[i]; }

  const int T = 256;

  // ---- pre-passes ----
  build_node_bf<<<(NVV * 40 + T - 1) / T, T, 0, stream>>>(var_learned, var_lp, var_comb_bf, NVV);
  build_node_bf<<<(NCC * 40 + T - 1) / T, T, 0, stream>>>(con_learned, con_lp, con_comb_bf, NCC);
  build_edge_bf<<<(NEE * 40 + T - 1) / T, T, 0, stream>>>(edge_learned, lo, hi, dm, wo, edge_comb_bf);
  convert_weights<<<18 * 80, T, 0, stream>>>(jobs);

  // ---- CSR builds (both convs; independent of GEMMs) ----
  zero2<<<(NVV + T - 1) / T, T, 0, stream>>>(countsC, NCC, countsV, NVV);
  hist2<<<(NEE + T - 1) / T, T, 0, stream>>>(eic, countsC, eiv, countsV, NEE);
  csr_scan<<<1, 256, 0, stream>>>(countsC, offC, curC, NCC);
  csr_scan<<<1, 256, 0, stream>>>(countsV, offV, curV, NVV);
  csr_scatter<<<(NEE + T - 1) / T, T, 0, stream>>>(eic, eiv, curC, ceA, csA, NEE);
  csr_scatter<<<(NEE + T - 1) / T, T, 0, stream>>>(eiv, eic, curV, ceB, csB, NEE);

  // ================= Stage A: con update (src=var, dst=con) =================
  gemm(con_comb_bf, WT[0], cu_bq, bufC1, nullptr, 0, 0, nullptr, nullptr, nullptr, nullptr, NCC, 0, stream); // q_c
  gemm(con_comb_bf, WT[4], cu_bs, bufC2, nullptr, 0, 0, nullptr, nullptr, nullptr, nullptr, NCC, 0, stream); // skip_c
  gemm(var_comb_bf, WT[1], cu_bk, bufV1, nullptr, 0, 0, nullptr, nullptr, nullptr, nullptr, NVV, 0, stream); // k_v
  gemm(var_comb_bf, WT[2], cu_bv, bufV2, nullptr, 0, 0, nullptr, nullptr, nullptr, nullptr, NVV, 0, stream); // v_v
  gemm(edge_comb_bf, WT[3], nullptr, nullptr, ee_bf, 128, 0, nullptr, nullptr, nullptr, nullptr, NEE, 0, stream); // ee bf16
  fused_attn<<<(NCC + 3) / 4, 256, 0, stream>>>(bufC1, bufV1, bufV2, ee_bf, offC, ceA, csA,
                                                bufC2, out_con, con_comb_bf, NCC);

  // ================= Stage B: var update (src=new con, dst=var) =================
  gemm(var_comb_bf, WT[5], vu_bq, bufV1, nullptr, 0, 0, nullptr, nullptr, nullptr, nullptr, NVV, 0, stream); // q_v
  gemm(var_comb_bf, WT[9], vu_bs, bufV2, nullptr, 0, 0, nullptr, nullptr, nullptr, nullptr, NVV, 0, stream); // skip_v
  gemm(con_comb_bf, WT[6], vu_bk, bufC1, nullptr, 0, 0, nullptr, nullptr, nullptr, nullptr, NCC, 0, stream); // k_c
  gemm(con_comb_bf, WT[7], vu_bv, bufC2, nullptr, 0, 0, nullptr, nullptr, nullptr, nullptr, NCC, 0, stream); // v_c
  gemm(edge_comb_bf, WT[8], nullptr, nullptr, ee_bf, 128, 0, nullptr, nullptr, nullptr, nullptr, NEE, 0, stream); // ee2 bf16
  fused_attn<<<(NVV + 3) / 4, 256, 0, stream>>>(bufV1, bufC1, bufC2, ee_bf, offV, ceB, csB,
                                                bufV2, out_var, var_comb_bf, NVV);

  // ================= Edge stage =================
  gemm(var_comb_bf, WT[10], eu_vb1, nullptr, hidV_bf, KP, 1, nullptr, nullptr, nullptr, nullptr, NVV, 1, stream);
  gemm(hidV_bf, WT[11], eu_vb2, nullptr, vc_bf, KP, 1, nullptr, nullptr, nullptr, nullptr, NVV, 1, stream);      // vc
  gemm(vc_bf, WT[15], nullptr, bufV1, nullptr, 0, 0, nullptr, nullptr, nullptr, nullptr, NVV, 0, stream);        // vcW
  gemm(con_comb_bf, WT[12], eu_cb1, nullptr, hidC_bf, KP, 1, nullptr, nullptr, nullptr, nullptr, NCC, 1, stream);
  gemm(hidC_bf, WT[13], eu_cb2, nullptr, cc_bf, KP, 1, nullptr, nullptr, nullptr, nullptr, NCC, 1, stream);      // cc
  gemm(cc_bf, WT[16], nullptr, bufC1, nullptr, 0, 0, nullptr, nullptr, nullptr, nullptr, NCC, 0, stream);        // ccW
  // t_e fused: edge_comb @ eW1[0:136] + vcW[eiv] + ccW[eic] + b1, relu -> bf16 [NE,160]
  gemm(edge_comb_bf, WT[14], eu_eb1, nullptr, te_bf, KP, 1, bufV1, bufC1, eiv, eic, NEE, 1, stream);
  gemm(te_bf, WT[17], eu_eb2, out_edge, nullptr, 0, 0, nullptr, nullptr, nullptr, nullptr, NEE, 1, stream);      // edge_new
}